// Round 6
// baseline (219.037 us; speedup 1.0000x reference)
//
#include <hip/hip_runtime.h>
#include <math.h>

#define J 24
#define RES 128
#define DHW (RES*RES*RES)
#define NBINS (128*128*16)   // key = (z0<<11) | (y0<<4) | (x0>>3)

__device__ __constant__ int PARENTS[J] = {-1,0,0,0,1,2,3,4,5,6,7,8,9,9,9,12,13,14,16,17,18,19,20,21};

struct __attribute__((packed, aligned(4))) f2u {
    float x, y;
};

// Compose two 3x4 affines: out = a @ b
__device__ inline void compose34(const float* a, const float* b, float* r) {
    for (int i = 0; i < 3; ++i) {
        float a0 = a[i*4+0], a1 = a[i*4+1], a2 = a[i*4+2], a3 = a[i*4+3];
        r[i*4+0] = a0*b[0] + a1*b[4] + a2*b[8];
        r[i*4+1] = a0*b[1] + a1*b[5] + a2*b[9];
        r[i*4+2] = a0*b[2] + a1*b[6] + a2*b[10];
        r[i*4+3] = a0*b[3] + a1*b[7] + a2*b[11] + a3;
    }
}

// Kernel 1: rel transforms (B=4, J=24, 3x4) -> ws. Slot 0 = cano, 1..4 = batches.
__global__ void tf_kernel(const float* __restrict__ poses,
                          const float* __restrict__ cano_pose,
                          const float* __restrict__ rest_joints,
                          float* __restrict__ rel_out) {
    __shared__ float M[5][J][12];
    __shared__ float relj[J][3];
    __shared__ float cinv[J][12];
    const int t = threadIdx.x;

    if (t < J) {
        int p = PARENTS[t];
        for (int k = 0; k < 3; ++k) {
            float v = rest_joints[t*3+k];
            if (p >= 0) v -= rest_joints[p*3+k];
            relj[t][k] = v;
        }
    }
    __syncthreads();

    for (int task = t; task < 5*J; task += blockDim.x) {
        int s = task / J, j = task % J;
        const float* rv = (s == 0) ? (cano_pose + j*3) : (poses + ((s-1)*J + j)*3);
        float rx = rv[0], ry = rv[1], rz = rv[2];
        float ang = sqrtf(rx*rx + ry*ry + rz*rz) + 1e-8f;
        float ax = rx/ang, ay = ry/ang, az = rz/ang;
        float s_ = sinf(ang), c_ = cosf(ang), ic = 1.0f - c_;
        float* m = M[s][j];
        m[0]  = 1.0f - ic*(ay*ay + az*az);
        m[1]  = -s_*az + ic*ax*ay;
        m[2]  =  s_*ay + ic*ax*az;
        m[3]  = relj[j][0];
        m[4]  =  s_*az + ic*ax*ay;
        m[5]  = 1.0f - ic*(ax*ax + az*az);
        m[6]  = -s_*ax + ic*ay*az;
        m[7]  = relj[j][1];
        m[8]  = -s_*ay + ic*ax*az;
        m[9]  =  s_*ax + ic*ay*az;
        m[10] = 1.0f - ic*(ax*ax + ay*ay);
        m[11] = relj[j][2];
    }
    __syncthreads();

    if (t < 5) {
        for (int i = 1; i < J; ++i) {
            int p = PARENTS[i];
            float r[12];
            compose34(M[t][p], M[t][i], r);
            for (int k = 0; k < 12; ++k) M[t][i][k] = r[k];
        }
    }
    __syncthreads();

    for (int task = t; task < 5*J; task += blockDim.x) {
        int s = task / J, j = task % J;
        float* m = M[s][j];
        float rjx = rest_joints[j*3], rjy = rest_joints[j*3+1], rjz = rest_joints[j*3+2];
        m[3]  -= m[0]*rjx + m[1]*rjy + m[2]*rjz;
        m[7]  -= m[4]*rjx + m[5]*rjy + m[6]*rjz;
        m[11] -= m[8]*rjx + m[9]*rjy + m[10]*rjz;
    }
    __syncthreads();

    if (t < J) {
        const float* m = M[0][t];
        float* ci = cinv[t];
        ci[0] = m[0]; ci[1] = m[4]; ci[2]  = m[8];
        ci[4] = m[1]; ci[5] = m[5]; ci[6]  = m[9];
        ci[8] = m[2]; ci[9] = m[6]; ci[10] = m[10];
        ci[3]  = -(ci[0]*m[3] + ci[1]*m[7] + ci[2]*m[11]);
        ci[7]  = -(ci[4]*m[3] + ci[5]*m[7] + ci[6]*m[11]);
        ci[11] = -(ci[8]*m[3] + ci[9]*m[7] + ci[10]*m[11]);
    }
    __syncthreads();

    for (int task = t; task < 4*J; task += blockDim.x) {
        int b = task / J, j = task % J;
        float r[12];
        compose34(M[b+1][j], cinv[j], r);
        for (int k = 0; k < 12; ++k) rel_out[(b*J + j)*12 + k] = r[k];
    }
}

__global__ void zero_kernel(unsigned int* __restrict__ p, int n) {
    int i = blockIdx.x * blockDim.x + threadIdx.x;
    if (i < n) p[i] = 0;
}

// point -> main-grid coords
__device__ inline void main_grid_coords(float vx, float vy, float vz,
                                        float bcx, float bcy, float bcz, float be,
                                        float& px, float& py, float& pz,
                                        int& x0, int& y0, int& z0,
                                        float& tx, float& ty, float& tz) {
    px = (vx - bcx) / be * 2.0f;
    py = (vy - bcy) / be * 2.0f;
    pz = (vz - bcz) / be * 2.0f;
    const float S = (float)RES;
    float fx = ((px + 1.0f) * S - 1.0f) * 0.5f;
    float fy = ((py + 1.0f) * S - 1.0f) * 0.5f;
    float fz = ((pz + 1.0f) * S - 1.0f) * 0.5f;
    fx = fminf(fmaxf(fx, 0.0f), S - 1.0f);
    fy = fminf(fmaxf(fy, 0.0f), S - 1.0f);
    fz = fminf(fmaxf(fz, 0.0f), S - 1.0f);
    float x0f = floorf(fx), y0f = floorf(fy), z0f = floorf(fz);
    tx = fx - x0f; ty = fy - y0f; tz = fz - z0f;
    x0 = (int)x0f; y0 = (int)y0f; z0 = (int)z0f;
}

// Kernel 2: per-point bin key + histogram. key = (z0<<11)|(y0<<4)|(x0>>3)
__global__ __launch_bounds__(256) void key_kernel(
    const float* __restrict__ verts,
    const float* __restrict__ bbox_extend, const float* __restrict__ bbox_center,
    unsigned int* __restrict__ keys, unsigned int* __restrict__ hist, int total) {
    int i = blockIdx.x * blockDim.x + threadIdx.x;
    if (i >= total) return;
    float vx = verts[(size_t)i*3+0], vy = verts[(size_t)i*3+1], vz = verts[(size_t)i*3+2];
    float px, py, pz, tx, ty, tz;
    int x0, y0, z0;
    main_grid_coords(vx, vy, vz, bbox_center[0], bbox_center[1], bbox_center[2],
                     bbox_extend[0], px, py, pz, x0, y0, z0, tx, ty, tz);
    unsigned int key = ((unsigned)z0 << 11) | ((unsigned)y0 << 4) | ((unsigned)x0 >> 3);
    keys[i] = key;
    atomicAdd(&hist[key], 1u);
}

// Kernel 3: exclusive scan of NBINS histogram (single block, 1024 thr, 2-pass per chunk)
__global__ __launch_bounds__(1024) void scan_kernel(
    const unsigned int* __restrict__ hist, unsigned int* __restrict__ cursor) {
    __shared__ unsigned int partial[1024];
    const int t = threadIdx.x;
    const int CHUNK = NBINS / 1024;   // 256
    const int base = t * CHUNK;
    unsigned int s = 0;
    for (int k = 0; k < CHUNK; ++k) s += hist[base + k];
    partial[t] = s;
    __syncthreads();
    for (int off = 1; off < 1024; off <<= 1) {
        unsigned int v = (t >= off) ? partial[t - off] : 0u;
        __syncthreads();
        partial[t] += v;
        __syncthreads();
    }
    unsigned int run = partial[t] - s;   // exclusive prefix of this chunk
    for (int k = 0; k < CHUNK; ++k) {
        cursor[base + k] = run;
        run += hist[base + k];
    }
}

// Kernel 4: scatter point ids into bin order
__global__ __launch_bounds__(256) void scatter_kernel(
    const unsigned int* __restrict__ keys, unsigned int* __restrict__ cursor,
    unsigned int* __restrict__ order, int total) {
    int i = blockIdx.x * blockDim.x + threadIdx.x;
    if (i >= total) return;
    unsigned int key = keys[i];
    unsigned int pos = atomicAdd(&cursor[key], 1u);
    order[pos] = (unsigned int)i;
}

// hand-grid trilinear sample of 12 channels [c0, c0+12), original layout
__device__ inline void sample_hand12(const float* __restrict__ g, int c0,
                                     float cx, float cy, float cz, float* w12) {
    const float S = (float)RES;
    float fx = ((cx + 1.0f) * S - 1.0f) * 0.5f;
    float fy = ((cy + 1.0f) * S - 1.0f) * 0.5f;
    float fz = ((cz + 1.0f) * S - 1.0f) * 0.5f;
    fx = fminf(fmaxf(fx, 0.0f), S - 1.0f);
    fy = fminf(fmaxf(fy, 0.0f), S - 1.0f);
    fz = fminf(fmaxf(fz, 0.0f), S - 1.0f);
    float x0f = floorf(fx), y0f = floorf(fy), z0f = floorf(fz);
    float tx = fx - x0f, ty = fy - y0f, tz = fz - z0f;
    int x0 = (int)x0f, y0 = (int)y0f, z0 = (int)z0f;
    int x1 = x0 < RES-1 ? x0+1 : RES-1;
    int y1 = y0 < RES-1 ? y0+1 : RES-1;
    int z1 = z0 < RES-1 ? z0+1 : RES-1;
    int b00 = (z0*RES + y0)*RES;
    int b01 = (z0*RES + y1)*RES;
    int b10 = (z1*RES + y0)*RES;
    int b11 = (z1*RES + y1)*RES;
    float wx0 = 1.0f - tx, wx1 = tx;
    float wy0 = 1.0f - ty, wy1 = ty;
    float wz0 = 1.0f - tz, wz1 = tz;
    float w000 = wz0*wy0*wx0, w001 = wz0*wy0*wx1;
    float w010 = wz0*wy1*wx0, w011 = wz0*wy1*wx1;
    float w100 = wz1*wy0*wx0, w101 = wz1*wy0*wx1;
    float w110 = wz1*wy1*wx0, w111 = wz1*wy1*wx1;
    #pragma unroll
    for (int c = 0; c < 12; ++c) {
        const float* gc = g + (size_t)(c0 + c) * DHW;
        w12[c] = gc[b00+x0]*w000 + gc[b00+x1]*w001
               + gc[b01+x0]*w010 + gc[b01+x1]*w011
               + gc[b10+x0]*w100 + gc[b10+x1]*w101
               + gc[b11+x0]*w110 + gc[b11+x1]*w111;
    }
}

// Kernel 5: skin in sorted order, 2 lanes per point (12 channels each).
__global__ __launch_bounds__(256) void skin_sorted(
    const float* __restrict__ verts,
    const float* __restrict__ wgrid,
    const float* __restrict__ lgrid,
    const float* __restrict__ rgrid,
    const float* __restrict__ rel,
    const unsigned int* __restrict__ order,
    const float* __restrict__ bbox_extend, const float* __restrict__ bbox_center,
    const float* __restrict__ lhand_extend, const float* __restrict__ lhand_center,
    const float* __restrict__ rhand_extend, const float* __restrict__ rhand_center,
    float* __restrict__ out, int N, int total) {
    // rel staged transposed: srel_t[(j*12+k)*4 + b]  -> divergent-b lanes hit
    // distinct banks (stride-1 in b), killing the 4-way conflict.
    __shared__ float srel_t[J*12*4];
    for (int i = threadIdx.x; i < 4*J*12; i += blockDim.x) {
        int b = i & 3, jk = i >> 2;
        srel_t[i] = rel[b*J*12 + jk];
    }
    __syncthreads();

    int gid = blockIdx.x * blockDim.x + threadIdx.x;
    int sid = gid >> 1;          // sorted position
    int half = gid & 1;          // 0: ch 0-11, 1: ch 12-23
    if (sid >= total) return;
    int pid = (int)order[sid];
    int b = pid / N;

    float vx = verts[(size_t)pid*3 + 0];
    float vy = verts[(size_t)pid*3 + 1];
    float vz = verts[(size_t)pid*3 + 2];

    float px, py, pz, tx, ty, tz;
    int x0, y0, z0;
    main_grid_coords(vx, vy, vz, bbox_center[0], bbox_center[1], bbox_center[2],
                     bbox_extend[0], px, py, pz, x0, y0, z0, tx, ty, tz);
    int y1 = y0 < RES-1 ? y0+1 : RES-1;
    int z1 = z0 < RES-1 ? z0+1 : RES-1;
    int b00 = (z0*RES + y0)*RES;
    int b01 = (z0*RES + y1)*RES;
    int b10 = (z1*RES + y0)*RES;
    int b11 = (z1*RES + y1)*RES;
    float wx0 = 1.0f - tx, wx1 = tx;
    float wy0 = 1.0f - ty, wy1 = ty;
    float wz0 = 1.0f - tz, wz1 = tz;
    float r00 = wz0*wy0, r01 = wz0*wy1, r10 = wz1*wy0, r11 = wz1*wy1;

    // x-pair load: xb = min(x0,126); value@x0 = (x0==127)? v.y : v.x;
    // value@x1 uses v.y always (weight tx==0 when x0==127).
    int xb = x0 < 127 ? x0 : 126;
    bool hi = (x0 == 127);
    const int c0 = half * 12;

    float w[12];
    #pragma unroll
    for (int c = 0; c < 12; ++c) {
        const float* gc = wgrid + (size_t)(c0 + c) * DHW;
        f2u v00 = *(const f2u*)(gc + b00 + xb);
        f2u v01 = *(const f2u*)(gc + b01 + xb);
        f2u v10 = *(const f2u*)(gc + b10 + xb);
        f2u v11 = *(const f2u*)(gc + b11 + xb);
        float a00 = hi ? v00.y : v00.x;
        float a01 = hi ? v01.y : v01.x;
        float a10 = hi ? v10.y : v10.x;
        float a11 = hi ? v11.y : v11.x;
        w[c] = r00 * (wx0*a00 + wx1*v00.y)
             + r01 * (wx0*a01 + wx1*v01.y)
             + r10 * (wx0*a10 + wx1*v10.y)
             + r11 * (wx0*a11 + wx1*v11.y);
    }

    // hand overrides (clustered by the sort -> mostly wave-uniform)
    float le = lhand_extend[0];
    float plx = px*le + lhand_center[0];
    float ply = py*le + lhand_center[1];
    float plz = pz*le + lhand_center[2];
    if (plx >= -1.0f && plx <= 1.0f && ply >= -1.0f && ply <= 1.0f &&
        plz >= -1.0f && plz <= 1.0f) {
        sample_hand12(lgrid, c0, plx, ply, plz, w);
    }
    float re = rhand_extend[0];
    float prx = px*re + rhand_center[0];
    float pry = py*re + rhand_center[1];
    float prz = pz*re + rhand_center[2];
    if (prx >= -1.0f && prx <= 1.0f && pry >= -1.0f && pry <= 1.0f &&
        prz >= -1.0f && prz <= 1.0f) {
        sample_hand12(rgrid, c0, prx, pry, prz, w);
    }

    // partial blend over this lane's 12 channels
    float m[12];
    #pragma unroll
    for (int k = 0; k < 12; ++k) m[k] = 0.0f;
    #pragma unroll
    for (int c = 0; c < 12; ++c) {
        float wj = w[c];
        const float* rj = &srel_t[((c0 + c)*12)*4 + b];
        #pragma unroll
        for (int k = 0; k < 12; ++k) m[k] += wj * rj[k*4];
    }
    // merge partner lane's half
    #pragma unroll
    for (int k = 0; k < 12; ++k) m[k] += __shfl_xor(m[k], 1);

    if (half == 0) {
        out[(size_t)pid*3 + 0] = m[0]*vx + m[1]*vy + m[2]*vz  + m[3];
        out[(size_t)pid*3 + 1] = m[4]*vx + m[5]*vy + m[6]*vz  + m[7];
        out[(size_t)pid*3 + 2] = m[8]*vx + m[9]*vy + m[10]*vz + m[11];
    }
}

extern "C" void kernel_launch(void* const* d_in, const int* in_sizes, int n_in,
                              void* d_out, int out_size, void* d_ws, size_t ws_size,
                              hipStream_t stream) {
    const float* verts       = (const float*)d_in[0];
    const float* poses       = (const float*)d_in[1];
    const float* cano_pose   = (const float*)d_in[2];
    const float* rest_joints = (const float*)d_in[3];
    const float* wgrid       = (const float*)d_in[4];
    const float* lgrid       = (const float*)d_in[5];
    const float* rgrid       = (const float*)d_in[6];
    const float* bbox_extend = (const float*)d_in[7];
    const float* bbox_center = (const float*)d_in[8];
    const float* lhand_extend= (const float*)d_in[9];
    const float* lhand_center= (const float*)d_in[10];
    const float* rhand_extend= (const float*)d_in[11];
    const float* rhand_center= (const float*)d_in[12];

    float* out = (float*)d_out;

    const int B = 4;
    const int total = in_sizes[0] / 3;
    const int N = total / B;

    // workspace layout
    char* ws = (char*)d_ws;
    float*        rel    = (float*)(ws);                                 // 4.6 KB
    unsigned int* hist   = (unsigned int*)(ws + 8192);                   // 1 MB
    unsigned int* cursor = (unsigned int*)(ws + 8192 + NBINS*4);         // 1 MB
    unsigned int* keys   = (unsigned int*)(ws + 8192 + 2*(size_t)NBINS*4);
    unsigned int* order  = (unsigned int*)(ws + 8192 + 2*(size_t)NBINS*4 + (size_t)total*4);

    const int block = 256;
    const int pgrid = (total + block - 1) / block;

    tf_kernel<<<1, 128, 0, stream>>>(poses, cano_pose, rest_joints, rel);
    zero_kernel<<<(NBINS + block - 1) / block, block, 0, stream>>>(hist, NBINS);
    key_kernel<<<pgrid, block, 0, stream>>>(verts, bbox_extend, bbox_center,
                                            keys, hist, total);
    scan_kernel<<<1, 1024, 0, stream>>>(hist, cursor);
    scatter_kernel<<<pgrid, block, 0, stream>>>(keys, cursor, order, total);

    const int sgrid = (total*2 + block - 1) / block;
    skin_sorted<<<sgrid, block, 0, stream>>>(
        verts, wgrid, lgrid, rgrid, rel, order,
        bbox_extend, bbox_center, lhand_extend, lhand_center,
        rhand_extend, rhand_center, out, N, total);
}

// Round 7
// 139.164 us; speedup vs baseline: 1.5739x; 1.5739x over previous
//
#include <hip/hip_runtime.h>
#include <hip/hip_fp16.h>
#include <math.h>

#define J 24
#define RES 128
#define DHW (RES*RES*RES)
#define CPAD 32   // padded channel count (fp16) -> 64 B per voxel, line aligned

typedef __attribute__((ext_vector_type(8))) unsigned short u16x8;
typedef __attribute__((ext_vector_type(4))) float f32x4;

__device__ __constant__ int PARENTS[J] = {-1,0,0,0,1,2,3,4,5,6,7,8,9,9,9,12,13,14,16,17,18,19,20,21};

__device__ inline float h2f(unsigned short u) {
    __half h;
    __builtin_memcpy(&h, &u, 2);
    return __half2float(h);
}
__device__ inline unsigned short f2h(float f) {
    __half h = __float2half(f);
    unsigned short u;
    __builtin_memcpy(&u, &h, 2);
    return u;
}

// Compose two 3x4 affines: out = a @ b
__device__ inline void compose34(const float* a, const float* b, float* r) {
    for (int i = 0; i < 3; ++i) {
        float a0 = a[i*4+0], a1 = a[i*4+1], a2 = a[i*4+2], a3 = a[i*4+3];
        r[i*4+0] = a0*b[0] + a1*b[4] + a2*b[8];
        r[i*4+1] = a0*b[1] + a1*b[5] + a2*b[9];
        r[i*4+2] = a0*b[2] + a1*b[6] + a2*b[10];
        r[i*4+3] = a0*b[3] + a1*b[7] + a2*b[11] + a3;
    }
}

// Kernel 1: rel transforms (B=4, J=24, 3x4) -> ws. Slot 0 = cano, 1..4 = batches.
__global__ void tf_kernel(const float* __restrict__ poses,
                          const float* __restrict__ cano_pose,
                          const float* __restrict__ rest_joints,
                          float* __restrict__ rel_out) {
    __shared__ float M[5][J][12];
    __shared__ float relj[J][3];
    __shared__ float cinv[J][12];
    const int t = threadIdx.x;

    if (t < J) {
        int p = PARENTS[t];
        for (int k = 0; k < 3; ++k) {
            float v = rest_joints[t*3+k];
            if (p >= 0) v -= rest_joints[p*3+k];
            relj[t][k] = v;
        }
    }
    __syncthreads();

    for (int task = t; task < 5*J; task += blockDim.x) {
        int s = task / J, j = task % J;
        const float* rv = (s == 0) ? (cano_pose + j*3) : (poses + ((s-1)*J + j)*3);
        float rx = rv[0], ry = rv[1], rz = rv[2];
        float ang = sqrtf(rx*rx + ry*ry + rz*rz) + 1e-8f;
        float ax = rx/ang, ay = ry/ang, az = rz/ang;
        float s_ = sinf(ang), c_ = cosf(ang), ic = 1.0f - c_;
        float* m = M[s][j];
        m[0]  = 1.0f - ic*(ay*ay + az*az);
        m[1]  = -s_*az + ic*ax*ay;
        m[2]  =  s_*ay + ic*ax*az;
        m[3]  = relj[j][0];
        m[4]  =  s_*az + ic*ax*ay;
        m[5]  = 1.0f - ic*(ax*ax + az*az);
        m[6]  = -s_*ax + ic*ay*az;
        m[7]  = relj[j][1];
        m[8]  = -s_*ay + ic*ax*az;
        m[9]  =  s_*ax + ic*ay*az;
        m[10] = 1.0f - ic*(ax*ax + ay*ay);
        m[11] = relj[j][2];
    }
    __syncthreads();

    if (t < 5) {
        for (int i = 1; i < J; ++i) {
            int p = PARENTS[i];
            float r[12];
            compose34(M[t][p], M[t][i], r);
            for (int k = 0; k < 12; ++k) M[t][i][k] = r[k];
        }
    }
    __syncthreads();

    for (int task = t; task < 5*J; task += blockDim.x) {
        int s = task / J, j = task % J;
        float* m = M[s][j];
        float rjx = rest_joints[j*3], rjy = rest_joints[j*3+1], rjz = rest_joints[j*3+2];
        m[3]  -= m[0]*rjx + m[1]*rjy + m[2]*rjz;
        m[7]  -= m[4]*rjx + m[5]*rjy + m[6]*rjz;
        m[11] -= m[8]*rjx + m[9]*rjy + m[10]*rjz;
    }
    __syncthreads();

    if (t < J) {
        const float* m = M[0][t];
        float* ci = cinv[t];
        ci[0] = m[0]; ci[1] = m[4]; ci[2]  = m[8];
        ci[4] = m[1]; ci[5] = m[5]; ci[6]  = m[9];
        ci[8] = m[2]; ci[9] = m[6]; ci[10] = m[10];
        ci[3]  = -(ci[0]*m[3] + ci[1]*m[7] + ci[2]*m[11]);
        ci[7]  = -(ci[4]*m[3] + ci[5]*m[7] + ci[6]*m[11]);
        ci[11] = -(ci[8]*m[3] + ci[9]*m[7] + ci[10]*m[11]);
    }
    __syncthreads();

    for (int task = t; task < 4*J; task += blockDim.x) {
        int b = task / J, j = task % J;
        float r[12];
        compose34(M[b+1][j], cinv[j], r);
        for (int k = 0; k < 12; ++k) rel_out[(b*J + j)*12 + k] = r[k];
    }
}

// Kernel 2: transpose [J][D][H][W] f32 -> [D][H][W][CPAD] fp16.
// Thread = (8-voxel group, channel-octet q). q<3: 16 nontemporal f32x4 loads,
// convert, 8 nontemporal 16B stores (write-combine, NO write-allocate/RFO).
// q==3 stores zeros into the pad (completes each 64B voxel line).
__global__ __launch_bounds__(256) void transpose_kernel(
    const float* __restrict__ g, unsigned short* __restrict__ tg) {
    int gid = blockIdx.x * blockDim.x + threadIdx.x;
    int grp = gid >> 2;
    int q   = gid & 3;
    int vbase = grp << 3;          // 8 voxels per group

    u16x8 o[8];
    #pragma unroll
    for (int i = 0; i < 8; ++i)
        #pragma unroll
        for (int k = 0; k < 8; ++k) o[i][k] = 0;

    if (q < 3) {
        #pragma unroll
        for (int k = 0; k < 8; ++k) {
            const float* plane = g + (size_t)(q*8 + k) * DHW + vbase;
            f32x4 a = __builtin_nontemporal_load((const f32x4*)plane);
            f32x4 b = __builtin_nontemporal_load((const f32x4*)(plane + 4));
            o[0][k] = f2h(a[0]); o[1][k] = f2h(a[1]);
            o[2][k] = f2h(a[2]); o[3][k] = f2h(a[3]);
            o[4][k] = f2h(b[0]); o[5][k] = f2h(b[1]);
            o[6][k] = f2h(b[2]); o[7][k] = f2h(b[3]);
        }
    }
    unsigned short* dst = tg + (size_t)vbase * CPAD + q * 8;
    #pragma unroll
    for (int i = 0; i < 8; ++i)
        __builtin_nontemporal_store(o[i], (u16x8*)(dst + i * CPAD));
}

// f32 original-layout trilinear sample (hand grids, rare)
__device__ inline void sample_grid_f32(const float* __restrict__ g,
                                       float cx, float cy, float cz, float* w) {
    const float S = (float)RES;
    float fx = ((cx + 1.0f) * S - 1.0f) * 0.5f;
    float fy = ((cy + 1.0f) * S - 1.0f) * 0.5f;
    float fz = ((cz + 1.0f) * S - 1.0f) * 0.5f;
    fx = fminf(fmaxf(fx, 0.0f), S - 1.0f);
    fy = fminf(fmaxf(fy, 0.0f), S - 1.0f);
    fz = fminf(fmaxf(fz, 0.0f), S - 1.0f);
    float x0f = floorf(fx), y0f = floorf(fy), z0f = floorf(fz);
    float tx = fx - x0f, ty = fy - y0f, tz = fz - z0f;
    int x0 = (int)x0f, y0 = (int)y0f, z0 = (int)z0f;
    int x1 = x0 < RES-1 ? x0+1 : RES-1;
    int y1 = y0 < RES-1 ? y0+1 : RES-1;
    int z1 = z0 < RES-1 ? z0+1 : RES-1;
    int b00 = (z0*RES + y0)*RES;
    int b01 = (z0*RES + y1)*RES;
    int b10 = (z1*RES + y0)*RES;
    int b11 = (z1*RES + y1)*RES;
    float wx0 = 1.0f - tx, wx1 = tx;
    float wy0 = 1.0f - ty, wy1 = ty;
    float wz0 = 1.0f - tz, wz1 = tz;
    float w000 = wz0*wy0*wx0, w001 = wz0*wy0*wx1;
    float w010 = wz0*wy1*wx0, w011 = wz0*wy1*wx1;
    float w100 = wz1*wy0*wx0, w101 = wz1*wy0*wx1;
    float w110 = wz1*wy1*wx0, w111 = wz1*wy1*wx1;
    #pragma unroll
    for (int c = 0; c < J; ++c) {
        const float* gc = g + (size_t)c * DHW;
        w[c] = gc[b00+x0]*w000 + gc[b00+x1]*w001
             + gc[b01+x0]*w010 + gc[b01+x1]*w011
             + gc[b10+x0]*w100 + gc[b10+x1]*w101
             + gc[b11+x0]*w110 + gc[b11+x1]*w111;
    }
}

// Kernel 3: gather from channel-innermost fp16 grid + blend + transform
__global__ __launch_bounds__(256) void skin_kernel(
    const float* __restrict__ verts,
    const unsigned short* __restrict__ tg,   // [DHW][CPAD] fp16
    const float* __restrict__ lgrid,
    const float* __restrict__ rgrid,
    const float* __restrict__ rel,
    const float* __restrict__ bbox_extend, const float* __restrict__ bbox_center,
    const float* __restrict__ lhand_extend, const float* __restrict__ lhand_center,
    const float* __restrict__ rhand_extend, const float* __restrict__ rhand_center,
    float* __restrict__ out, int N, int total) {
    __shared__ float srel[J*12];
    int gid = blockIdx.x * blockDim.x + threadIdx.x;
    int b = gid / N;   // uniform within a block (N % 256 == 0)

    for (int i = threadIdx.x; i < J*12; i += blockDim.x)
        srel[i] = rel[b*J*12 + i];
    __syncthreads();

    if (gid >= total) return;

    float vx = verts[(size_t)gid*3 + 0];
    float vy = verts[(size_t)gid*3 + 1];
    float vz = verts[(size_t)gid*3 + 2];

    float be = bbox_extend[0];
    float px = (vx - bbox_center[0]) / be * 2.0f;
    float py = (vy - bbox_center[1]) / be * 2.0f;
    float pz = (vz - bbox_center[2]) / be * 2.0f;

    const float S = (float)RES;
    float fx = ((px + 1.0f) * S - 1.0f) * 0.5f;
    float fy = ((py + 1.0f) * S - 1.0f) * 0.5f;
    float fz = ((pz + 1.0f) * S - 1.0f) * 0.5f;
    fx = fminf(fmaxf(fx, 0.0f), S - 1.0f);
    fy = fminf(fmaxf(fy, 0.0f), S - 1.0f);
    fz = fminf(fmaxf(fz, 0.0f), S - 1.0f);
    float x0f = floorf(fx), y0f = floorf(fy), z0f = floorf(fz);
    float tx = fx - x0f, ty = fy - y0f, tz = fz - z0f;
    int x0 = (int)x0f, y0 = (int)y0f, z0 = (int)z0f;
    int x1 = x0 < RES-1 ? x0+1 : RES-1;
    int y1 = y0 < RES-1 ? y0+1 : RES-1;
    int z1 = z0 < RES-1 ? z0+1 : RES-1;

    float w[J];
    #pragma unroll
    for (int c = 0; c < J; ++c) w[c] = 0.0f;

    #pragma unroll
    for (int dz = 0; dz < 2; ++dz) {
        int zz = dz ? z1 : z0;
        float wz = dz ? tz : 1.0f - tz;
        #pragma unroll
        for (int dy = 0; dy < 2; ++dy) {
            int yy = dy ? y1 : y0;
            float wzy = wz * (dy ? ty : 1.0f - ty);
            #pragma unroll
            for (int dx = 0; dx < 2; ++dx) {
                int xx = dx ? x1 : x0;
                float wc = wzy * (dx ? tx : 1.0f - tx);
                const unsigned short* vp = tg + ((size_t)((zz*RES + yy)*RES + xx) * CPAD);
                u16x8 a0 = *(const u16x8*)(vp);
                u16x8 a1 = *(const u16x8*)(vp + 8);
                u16x8 a2 = *(const u16x8*)(vp + 16);
                #pragma unroll
                for (int k = 0; k < 8; ++k) {
                    w[k +  0] += wc * h2f(a0[k]);
                    w[k +  8] += wc * h2f(a1[k]);
                    w[k + 16] += wc * h2f(a2[k]);
                }
            }
        }
    }

    // hand overrides (rare: ~0.6% of points each)
    float le = lhand_extend[0];
    float plx = px*le + lhand_center[0];
    float ply = py*le + lhand_center[1];
    float plz = pz*le + lhand_center[2];
    if (plx >= -1.0f && plx <= 1.0f && ply >= -1.0f && ply <= 1.0f &&
        plz >= -1.0f && plz <= 1.0f) {
        sample_grid_f32(lgrid, plx, ply, plz, w);
    }
    float re = rhand_extend[0];
    float prx = px*re + rhand_center[0];
    float pry = py*re + rhand_center[1];
    float prz = pz*re + rhand_center[2];
    if (prx >= -1.0f && prx <= 1.0f && pry >= -1.0f && pry <= 1.0f &&
        prz >= -1.0f && prz <= 1.0f) {
        sample_grid_f32(rgrid, prx, pry, prz, w);
    }

    // blend: M = sum_j w[j] * rel[b][j]
    float m[12];
    #pragma unroll
    for (int k = 0; k < 12; ++k) m[k] = 0.0f;
    #pragma unroll
    for (int j = 0; j < J; ++j) {
        float wj = w[j];
        const float* rj = &srel[j*12];
        #pragma unroll
        for (int k = 0; k < 12; ++k) m[k] += wj * rj[k];
    }

    float ox = m[0]*vx + m[1]*vy + m[2]*vz  + m[3];
    float oy = m[4]*vx + m[5]*vy + m[6]*vz  + m[7];
    float oz = m[8]*vx + m[9]*vy + m[10]*vz + m[11];

    out[(size_t)gid*3 + 0] = ox;
    out[(size_t)gid*3 + 1] = oy;
    out[(size_t)gid*3 + 2] = oz;
}

// Fallback (original f32-layout path) if workspace is too small
__global__ __launch_bounds__(256) void skin_kernel_f32(
    const float* __restrict__ verts,
    const float* __restrict__ wgrid,
    const float* __restrict__ lgrid,
    const float* __restrict__ rgrid,
    const float* __restrict__ rel,
    const float* __restrict__ bbox_extend, const float* __restrict__ bbox_center,
    const float* __restrict__ lhand_extend, const float* __restrict__ lhand_center,
    const float* __restrict__ rhand_extend, const float* __restrict__ rhand_center,
    float* __restrict__ out, int N, int total) {
    __shared__ float srel[J*12];
    int gid = blockIdx.x * blockDim.x + threadIdx.x;
    int b = gid / N;
    for (int i = threadIdx.x; i < J*12; i += blockDim.x)
        srel[i] = rel[b*J*12 + i];
    __syncthreads();
    if (gid >= total) return;
    float vx = verts[(size_t)gid*3 + 0];
    float vy = verts[(size_t)gid*3 + 1];
    float vz = verts[(size_t)gid*3 + 2];
    float be = bbox_extend[0];
    float px = (vx - bbox_center[0]) / be * 2.0f;
    float py = (vy - bbox_center[1]) / be * 2.0f;
    float pz = (vz - bbox_center[2]) / be * 2.0f;
    float w[J];
    sample_grid_f32(wgrid, px, py, pz, w);
    float le = lhand_extend[0];
    float plx = px*le + lhand_center[0];
    float ply = py*le + lhand_center[1];
    float plz = pz*le + lhand_center[2];
    if (plx >= -1.0f && plx <= 1.0f && ply >= -1.0f && ply <= 1.0f &&
        plz >= -1.0f && plz <= 1.0f) sample_grid_f32(lgrid, plx, ply, plz, w);
    float re = rhand_extend[0];
    float prx = px*re + rhand_center[0];
    float pry = py*re + rhand_center[1];
    float prz = pz*re + rhand_center[2];
    if (prx >= -1.0f && prx <= 1.0f && pry >= -1.0f && pry <= 1.0f &&
        prz >= -1.0f && prz <= 1.0f) sample_grid_f32(rgrid, prx, pry, prz, w);
    float m[12];
    #pragma unroll
    for (int k = 0; k < 12; ++k) m[k] = 0.0f;
    #pragma unroll
    for (int j = 0; j < J; ++j) {
        float wj = w[j];
        const float* rj = &srel[j*12];
        #pragma unroll
        for (int k = 0; k < 12; ++k) m[k] += wj * rj[k];
    }
    out[(size_t)gid*3 + 0] = m[0]*vx + m[1]*vy + m[2]*vz  + m[3];
    out[(size_t)gid*3 + 1] = m[4]*vx + m[5]*vy + m[6]*vz  + m[7];
    out[(size_t)gid*3 + 2] = m[8]*vx + m[9]*vy + m[10]*vz + m[11];
}

extern "C" void kernel_launch(void* const* d_in, const int* in_sizes, int n_in,
                              void* d_out, int out_size, void* d_ws, size_t ws_size,
                              hipStream_t stream) {
    const float* verts       = (const float*)d_in[0];
    const float* poses       = (const float*)d_in[1];
    const float* cano_pose   = (const float*)d_in[2];
    const float* rest_joints = (const float*)d_in[3];
    const float* wgrid       = (const float*)d_in[4];
    const float* lgrid       = (const float*)d_in[5];
    const float* rgrid       = (const float*)d_in[6];
    const float* bbox_extend = (const float*)d_in[7];
    const float* bbox_center = (const float*)d_in[8];
    const float* lhand_extend= (const float*)d_in[9];
    const float* lhand_center= (const float*)d_in[10];
    const float* rhand_extend= (const float*)d_in[11];
    const float* rhand_center= (const float*)d_in[12];

    float* out = (float*)d_out;
    float* rel = (float*)d_ws;                         // 4608 B
    unsigned short* tg = (unsigned short*)((char*)d_ws + 8192); // [DHW][CPAD] fp16

    const int B = 4;
    const int total = in_sizes[0] / 3;
    const int N = total / B;
    const size_t need = 8192 + (size_t)DHW * CPAD * 2;

    tf_kernel<<<1, 128, 0, stream>>>(poses, cano_pose, rest_joints, rel);

    const int block = 256;
    if (ws_size >= need) {
        // DHW/8 groups * 4 threads = DHW/2 threads
        transpose_kernel<<<(DHW / 2) / block, block, 0, stream>>>(wgrid, tg);
        skin_kernel<<<(total + block - 1) / block, block, 0, stream>>>(
            verts, tg, lgrid, rgrid, rel,
            bbox_extend, bbox_center, lhand_extend, lhand_center,
            rhand_extend, rhand_center, out, N, total);
    } else {
        skin_kernel_f32<<<(total + block - 1) / block, block, 0, stream>>>(
            verts, wgrid, lgrid, rgrid, rel,
            bbox_extend, bbox_center, lhand_extend, lhand_center,
            rhand_extend, rhand_center, out, N, total);
    }
}

// Round 8
// 120.395 us; speedup vs baseline: 1.8193x; 1.1559x over previous
//
#include <hip/hip_runtime.h>
#include <hip/hip_fp16.h>
#include <math.h>

#define J 24
#define RES 128
#define DHW (RES*RES*RES)
#define CPAD 32   // padded channel count (fp16) -> 64 B per voxel, line aligned

typedef __attribute__((ext_vector_type(8))) unsigned short u16x8;
typedef __attribute__((ext_vector_type(4))) float f32x4;

__device__ __constant__ int PARENTS[J] = {-1,0,0,0,1,2,3,4,5,6,7,8,9,9,9,12,13,14,16,17,18,19,20,21};

__device__ inline float h2f(unsigned short u) {
    __half h;
    __builtin_memcpy(&h, &u, 2);
    return __half2float(h);
}
__device__ inline unsigned short f2h(float f) {
    __half h = __float2half(f);
    unsigned short u;
    __builtin_memcpy(&u, &h, 2);
    return u;
}

// Compose two 3x4 affines: out = a @ b
__device__ inline void compose34(const float* a, const float* b, float* r) {
    for (int i = 0; i < 3; ++i) {
        float a0 = a[i*4+0], a1 = a[i*4+1], a2 = a[i*4+2], a3 = a[i*4+3];
        r[i*4+0] = a0*b[0] + a1*b[4] + a2*b[8];
        r[i*4+1] = a0*b[1] + a1*b[5] + a2*b[9];
        r[i*4+2] = a0*b[2] + a1*b[6] + a2*b[10];
        r[i*4+3] = a0*b[3] + a1*b[7] + a2*b[11] + a3;
    }
}

// Kernel 1: rel transforms (B=4, J=24, 3x4) -> ws. Slot 0 = cano, 1..4 = batches.
__global__ void tf_kernel(const float* __restrict__ poses,
                          const float* __restrict__ cano_pose,
                          const float* __restrict__ rest_joints,
                          float* __restrict__ rel_out) {
    __shared__ float M[5][J][12];
    __shared__ float relj[J][3];
    __shared__ float cinv[J][12];
    const int t = threadIdx.x;

    if (t < J) {
        int p = PARENTS[t];
        for (int k = 0; k < 3; ++k) {
            float v = rest_joints[t*3+k];
            if (p >= 0) v -= rest_joints[p*3+k];
            relj[t][k] = v;
        }
    }
    __syncthreads();

    for (int task = t; task < 5*J; task += blockDim.x) {
        int s = task / J, j = task % J;
        const float* rv = (s == 0) ? (cano_pose + j*3) : (poses + ((s-1)*J + j)*3);
        float rx = rv[0], ry = rv[1], rz = rv[2];
        float ang = sqrtf(rx*rx + ry*ry + rz*rz) + 1e-8f;
        float ax = rx/ang, ay = ry/ang, az = rz/ang;
        float s_ = sinf(ang), c_ = cosf(ang), ic = 1.0f - c_;
        float* m = M[s][j];
        m[0]  = 1.0f - ic*(ay*ay + az*az);
        m[1]  = -s_*az + ic*ax*ay;
        m[2]  =  s_*ay + ic*ax*az;
        m[3]  = relj[j][0];
        m[4]  =  s_*az + ic*ax*ay;
        m[5]  = 1.0f - ic*(ax*ax + az*az);
        m[6]  = -s_*ax + ic*ay*az;
        m[7]  = relj[j][1];
        m[8]  = -s_*ay + ic*ax*az;
        m[9]  =  s_*ax + ic*ay*az;
        m[10] = 1.0f - ic*(ax*ax + ay*ay);
        m[11] = relj[j][2];
    }
    __syncthreads();

    if (t < 5) {
        for (int i = 1; i < J; ++i) {
            int p = PARENTS[i];
            float r[12];
            compose34(M[t][p], M[t][i], r);
            for (int k = 0; k < 12; ++k) M[t][i][k] = r[k];
        }
    }
    __syncthreads();

    for (int task = t; task < 5*J; task += blockDim.x) {
        int s = task / J, j = task % J;
        float* m = M[s][j];
        float rjx = rest_joints[j*3], rjy = rest_joints[j*3+1], rjz = rest_joints[j*3+2];
        m[3]  -= m[0]*rjx + m[1]*rjy + m[2]*rjz;
        m[7]  -= m[4]*rjx + m[5]*rjy + m[6]*rjz;
        m[11] -= m[8]*rjx + m[9]*rjy + m[10]*rjz;
    }
    __syncthreads();

    if (t < J) {
        const float* m = M[0][t];
        float* ci = cinv[t];
        ci[0] = m[0]; ci[1] = m[4]; ci[2]  = m[8];
        ci[4] = m[1]; ci[5] = m[5]; ci[6]  = m[9];
        ci[8] = m[2]; ci[9] = m[6]; ci[10] = m[10];
        ci[3]  = -(ci[0]*m[3] + ci[1]*m[7] + ci[2]*m[11]);
        ci[7]  = -(ci[4]*m[3] + ci[5]*m[7] + ci[6]*m[11]);
        ci[11] = -(ci[8]*m[3] + ci[9]*m[7] + ci[10]*m[11]);
    }
    __syncthreads();

    for (int task = t; task < 4*J; task += blockDim.x) {
        int b = task / J, j = task % J;
        float r[12];
        compose34(M[b+1][j], cinv[j], r);
        for (int k = 0; k < 12; ++k) rel_out[(b*J + j)*12 + k] = r[k];
    }
}

// Kernel 2: transpose [J][D][H][W] f32 -> [D][H][W][CPAD] fp16.
// 4 threads per 4-voxel group; thread q<3 handles channel-octet q via 8
// nontemporal f32x4 loads; q==3 zeros the pad. Normal (cached) stores so tg
// stays L2/L3-resident for the skin kernel.
// BLOCK SWIZZLE: concurrent blocks are spread ~128KB apart within each plane
// to decorrelate DRAM-channel usage across the 24 plane streams (all planes
// are 8MiB apart -> same channel set at equal v; in-order dispatch made the
// whole chip hammer a few channels).
__global__ __launch_bounds__(256) void transpose_kernel(
    const float* __restrict__ g, unsigned short* __restrict__ tg) {
    // gridDim.x == 8192 == 2^13; rotate-left-7 of the 13-bit block index.
    unsigned int bid = blockIdx.x;
    unsigned int sb = ((bid << 7) | (bid >> 6)) & 8191u;
    int gid = (int)(sb * blockDim.x + threadIdx.x);
    int grp = gid >> 2;
    int q   = gid & 3;
    int vbase = grp << 2;

    u16x8 o0, o1, o2, o3;
    #pragma unroll
    for (int k = 0; k < 8; ++k) { o0[k] = 0; o1[k] = 0; o2[k] = 0; o3[k] = 0; }

    if (q < 3) {
        #pragma unroll
        for (int k = 0; k < 8; ++k) {
            const f32x4* src = (const f32x4*)(g + (size_t)(q*8 + k) * DHW + vbase);
            f32x4 val = __builtin_nontemporal_load(src);
            o0[k] = f2h(val[0]);
            o1[k] = f2h(val[1]);
            o2[k] = f2h(val[2]);
            o3[k] = f2h(val[3]);
        }
    }
    unsigned short* dst = tg + (size_t)vbase * CPAD + q * 8;
    *(u16x8*)(dst)            = o0;
    *(u16x8*)(dst + CPAD)     = o1;
    *(u16x8*)(dst + 2*CPAD)   = o2;
    *(u16x8*)(dst + 3*CPAD)   = o3;
}

// f32 original-layout trilinear sample (hand grids, rare)
__device__ inline void sample_grid_f32(const float* __restrict__ g,
                                       float cx, float cy, float cz, float* w) {
    const float S = (float)RES;
    float fx = ((cx + 1.0f) * S - 1.0f) * 0.5f;
    float fy = ((cy + 1.0f) * S - 1.0f) * 0.5f;
    float fz = ((cz + 1.0f) * S - 1.0f) * 0.5f;
    fx = fminf(fmaxf(fx, 0.0f), S - 1.0f);
    fy = fminf(fmaxf(fy, 0.0f), S - 1.0f);
    fz = fminf(fmaxf(fz, 0.0f), S - 1.0f);
    float x0f = floorf(fx), y0f = floorf(fy), z0f = floorf(fz);
    float tx = fx - x0f, ty = fy - y0f, tz = fz - z0f;
    int x0 = (int)x0f, y0 = (int)y0f, z0 = (int)z0f;
    int x1 = x0 < RES-1 ? x0+1 : RES-1;
    int y1 = y0 < RES-1 ? y0+1 : RES-1;
    int z1 = z0 < RES-1 ? z0+1 : RES-1;
    int b00 = (z0*RES + y0)*RES;
    int b01 = (z0*RES + y1)*RES;
    int b10 = (z1*RES + y0)*RES;
    int b11 = (z1*RES + y1)*RES;
    float wx0 = 1.0f - tx, wx1 = tx;
    float wy0 = 1.0f - ty, wy1 = ty;
    float wz0 = 1.0f - tz, wz1 = tz;
    float w000 = wz0*wy0*wx0, w001 = wz0*wy0*wx1;
    float w010 = wz0*wy1*wx0, w011 = wz0*wy1*wx1;
    float w100 = wz1*wy0*wx0, w101 = wz1*wy0*wx1;
    float w110 = wz1*wy1*wx0, w111 = wz1*wy1*wx1;
    #pragma unroll
    for (int c = 0; c < J; ++c) {
        const float* gc = g + (size_t)c * DHW;
        w[c] = gc[b00+x0]*w000 + gc[b00+x1]*w001
             + gc[b01+x0]*w010 + gc[b01+x1]*w011
             + gc[b10+x0]*w100 + gc[b10+x1]*w101
             + gc[b11+x0]*w110 + gc[b11+x1]*w111;
    }
}

// Kernel 3: gather from channel-innermost fp16 grid + blend + transform
__global__ __launch_bounds__(256) void skin_kernel(
    const float* __restrict__ verts,
    const unsigned short* __restrict__ tg,   // [DHW][CPAD] fp16
    const float* __restrict__ lgrid,
    const float* __restrict__ rgrid,
    const float* __restrict__ rel,
    const float* __restrict__ bbox_extend, const float* __restrict__ bbox_center,
    const float* __restrict__ lhand_extend, const float* __restrict__ lhand_center,
    const float* __restrict__ rhand_extend, const float* __restrict__ rhand_center,
    float* __restrict__ out, int N, int total) {
    __shared__ float srel[J*12];
    int gid = blockIdx.x * blockDim.x + threadIdx.x;
    int b = gid / N;   // uniform within a block (N % 256 == 0)

    for (int i = threadIdx.x; i < J*12; i += blockDim.x)
        srel[i] = rel[b*J*12 + i];
    __syncthreads();

    if (gid >= total) return;

    float vx = verts[(size_t)gid*3 + 0];
    float vy = verts[(size_t)gid*3 + 1];
    float vz = verts[(size_t)gid*3 + 2];

    float be = bbox_extend[0];
    float px = (vx - bbox_center[0]) / be * 2.0f;
    float py = (vy - bbox_center[1]) / be * 2.0f;
    float pz = (vz - bbox_center[2]) / be * 2.0f;

    const float S = (float)RES;
    float fx = ((px + 1.0f) * S - 1.0f) * 0.5f;
    float fy = ((py + 1.0f) * S - 1.0f) * 0.5f;
    float fz = ((pz + 1.0f) * S - 1.0f) * 0.5f;
    fx = fminf(fmaxf(fx, 0.0f), S - 1.0f);
    fy = fminf(fmaxf(fy, 0.0f), S - 1.0f);
    fz = fminf(fmaxf(fz, 0.0f), S - 1.0f);
    float x0f = floorf(fx), y0f = floorf(fy), z0f = floorf(fz);
    float tx = fx - x0f, ty = fy - y0f, tz = fz - z0f;
    int x0 = (int)x0f, y0 = (int)y0f, z0 = (int)z0f;
    int x1 = x0 < RES-1 ? x0+1 : RES-1;
    int y1 = y0 < RES-1 ? y0+1 : RES-1;
    int z1 = z0 < RES-1 ? z0+1 : RES-1;

    float w[J];
    #pragma unroll
    for (int c = 0; c < J; ++c) w[c] = 0.0f;

    #pragma unroll
    for (int dz = 0; dz < 2; ++dz) {
        int zz = dz ? z1 : z0;
        float wz = dz ? tz : 1.0f - tz;
        #pragma unroll
        for (int dy = 0; dy < 2; ++dy) {
            int yy = dy ? y1 : y0;
            float wzy = wz * (dy ? ty : 1.0f - ty);
            #pragma unroll
            for (int dx = 0; dx < 2; ++dx) {
                int xx = dx ? x1 : x0;
                float wc = wzy * (dx ? tx : 1.0f - tx);
                const unsigned short* vp = tg + ((size_t)((zz*RES + yy)*RES + xx) * CPAD);
                u16x8 a0 = *(const u16x8*)(vp);
                u16x8 a1 = *(const u16x8*)(vp + 8);
                u16x8 a2 = *(const u16x8*)(vp + 16);
                #pragma unroll
                for (int k = 0; k < 8; ++k) {
                    w[k +  0] += wc * h2f(a0[k]);
                    w[k +  8] += wc * h2f(a1[k]);
                    w[k + 16] += wc * h2f(a2[k]);
                }
            }
        }
    }

    // hand overrides (rare: ~0.6% of points each)
    float le = lhand_extend[0];
    float plx = px*le + lhand_center[0];
    float ply = py*le + lhand_center[1];
    float plz = pz*le + lhand_center[2];
    if (plx >= -1.0f && plx <= 1.0f && ply >= -1.0f && ply <= 1.0f &&
        plz >= -1.0f && plz <= 1.0f) {
        sample_grid_f32(lgrid, plx, ply, plz, w);
    }
    float re = rhand_extend[0];
    float prx = px*re + rhand_center[0];
    float pry = py*re + rhand_center[1];
    float prz = pz*re + rhand_center[2];
    if (prx >= -1.0f && prx <= 1.0f && pry >= -1.0f && pry <= 1.0f &&
        prz >= -1.0f && prz <= 1.0f) {
        sample_grid_f32(rgrid, prx, pry, prz, w);
    }

    // blend: M = sum_j w[j] * rel[b][j]
    float m[12];
    #pragma unroll
    for (int k = 0; k < 12; ++k) m[k] = 0.0f;
    #pragma unroll
    for (int j = 0; j < J; ++j) {
        float wj = w[j];
        const float* rj = &srel[j*12];
        #pragma unroll
        for (int k = 0; k < 12; ++k) m[k] += wj * rj[k];
    }

    float ox = m[0]*vx + m[1]*vy + m[2]*vz  + m[3];
    float oy = m[4]*vx + m[5]*vy + m[6]*vz  + m[7];
    float oz = m[8]*vx + m[9]*vy + m[10]*vz + m[11];

    out[(size_t)gid*3 + 0] = ox;
    out[(size_t)gid*3 + 1] = oy;
    out[(size_t)gid*3 + 2] = oz;
}

// Fallback (original f32-layout path) if workspace is too small
__global__ __launch_bounds__(256) void skin_kernel_f32(
    const float* __restrict__ verts,
    const float* __restrict__ wgrid,
    const float* __restrict__ lgrid,
    const float* __restrict__ rgrid,
    const float* __restrict__ rel,
    const float* __restrict__ bbox_extend, const float* __restrict__ bbox_center,
    const float* __restrict__ lhand_extend, const float* __restrict__ lhand_center,
    const float* __restrict__ rhand_extend, const float* __restrict__ rhand_center,
    float* __restrict__ out, int N, int total) {
    __shared__ float srel[J*12];
    int gid = blockIdx.x * blockDim.x + threadIdx.x;
    int b = gid / N;
    for (int i = threadIdx.x; i < J*12; i += blockDim.x)
        srel[i] = rel[b*J*12 + i];
    __syncthreads();
    if (gid >= total) return;
    float vx = verts[(size_t)gid*3 + 0];
    float vy = verts[(size_t)gid*3 + 1];
    float vz = verts[(size_t)gid*3 + 2];
    float be = bbox_extend[0];
    float px = (vx - bbox_center[0]) / be * 2.0f;
    float py = (vy - bbox_center[1]) / be * 2.0f;
    float pz = (vz - bbox_center[2]) / be * 2.0f;
    float w[J];
    sample_grid_f32(wgrid, px, py, pz, w);
    float le = lhand_extend[0];
    float plx = px*le + lhand_center[0];
    float ply = py*le + lhand_center[1];
    float plz = pz*le + lhand_center[2];
    if (plx >= -1.0f && plx <= 1.0f && ply >= -1.0f && ply <= 1.0f &&
        plz >= -1.0f && plz <= 1.0f) sample_grid_f32(lgrid, plx, ply, plz, w);
    float re = rhand_extend[0];
    float prx = px*re + rhand_center[0];
    float pry = py*re + rhand_center[1];
    float prz = pz*re + rhand_center[2];
    if (prx >= -1.0f && prx <= 1.0f && pry >= -1.0f && pry <= 1.0f &&
        prz >= -1.0f && prz <= 1.0f) sample_grid_f32(rgrid, prx, pry, prz, w);
    float m[12];
    #pragma unroll
    for (int k = 0; k < 12; ++k) m[k] = 0.0f;
    #pragma unroll
    for (int j = 0; j < J; ++j) {
        float wj = w[j];
        const float* rj = &srel[j*12];
        #pragma unroll
        for (int k = 0; k < 12; ++k) m[k] += wj * rj[k];
    }
    out[(size_t)gid*3 + 0] = m[0]*vx + m[1]*vy + m[2]*vz  + m[3];
    out[(size_t)gid*3 + 1] = m[4]*vx + m[5]*vy + m[6]*vz  + m[7];
    out[(size_t)gid*3 + 2] = m[8]*vx + m[9]*vy + m[10]*vz + m[11];
}

extern "C" void kernel_launch(void* const* d_in, const int* in_sizes, int n_in,
                              void* d_out, int out_size, void* d_ws, size_t ws_size,
                              hipStream_t stream) {
    const float* verts       = (const float*)d_in[0];
    const float* poses       = (const float*)d_in[1];
    const float* cano_pose   = (const float*)d_in[2];
    const float* rest_joints = (const float*)d_in[3];
    const float* wgrid       = (const float*)d_in[4];
    const float* lgrid       = (const float*)d_in[5];
    const float* rgrid       = (const float*)d_in[6];
    const float* bbox_extend = (const float*)d_in[7];
    const float* bbox_center = (const float*)d_in[8];
    const float* lhand_extend= (const float*)d_in[9];
    const float* lhand_center= (const float*)d_in[10];
    const float* rhand_extend= (const float*)d_in[11];
    const float* rhand_center= (const float*)d_in[12];

    float* out = (float*)d_out;
    float* rel = (float*)d_ws;                         // 4608 B
    unsigned short* tg = (unsigned short*)((char*)d_ws + 8192); // [DHW][CPAD] fp16

    const int B = 4;
    const int total = in_sizes[0] / 3;
    const int N = total / B;
    const size_t need = 8192 + (size_t)DHW * CPAD * 2;

    tf_kernel<<<1, 128, 0, stream>>>(poses, cano_pose, rest_joints, rel);

    const int block = 256;
    if (ws_size >= need) {
        // threads = DHW (4 per 4-voxel group); blocks = DHW/256 = 8192
        transpose_kernel<<<DHW / block, block, 0, stream>>>(wgrid, tg);
        skin_kernel<<<(total + block - 1) / block, block, 0, stream>>>(
            verts, tg, lgrid, rgrid, rel,
            bbox_extend, bbox_center, lhand_extend, lhand_center,
            rhand_extend, rhand_center, out, N, total);
    } else {
        skin_kernel_f32<<<(total + block - 1) / block, block, 0, stream>>>(
            verts, wgrid, lgrid, rgrid, rel,
            bbox_extend, bbox_center, lhand_extend, lhand_center,
            rhand_extend, rhand_center, out, N, total);
    }
}

// Round 9
// 119.799 us; speedup vs baseline: 1.8284x; 1.0050x over previous
//
#include <hip/hip_runtime.h>
#include <hip/hip_fp16.h>
#include <math.h>

#define J 24
#define RES 128
#define DHW (RES*RES*RES)
#define CPAD 32    // padded channel count (fp16) -> 64 B per voxel, line aligned
#define TILE 512   // voxels per transpose block

typedef __attribute__((ext_vector_type(8))) unsigned short u16x8;

__device__ __constant__ int PARENTS[J] = {-1,0,0,0,1,2,3,4,5,6,7,8,9,9,9,12,13,14,16,17,18,19,20,21};

__device__ inline float h2f(unsigned short u) {
    __half h;
    __builtin_memcpy(&h, &u, 2);
    return __half2float(h);
}
__device__ inline unsigned short f2h(float f) {
    __half h = __float2half(f);
    unsigned short u;
    __builtin_memcpy(&u, &h, 2);
    return u;
}

// Compose two 3x4 affines: out = a @ b
__device__ inline void compose34(const float* a, const float* b, float* r) {
    for (int i = 0; i < 3; ++i) {
        float a0 = a[i*4+0], a1 = a[i*4+1], a2 = a[i*4+2], a3 = a[i*4+3];
        r[i*4+0] = a0*b[0] + a1*b[4] + a2*b[8];
        r[i*4+1] = a0*b[1] + a1*b[5] + a2*b[9];
        r[i*4+2] = a0*b[2] + a1*b[6] + a2*b[10];
        r[i*4+3] = a0*b[3] + a1*b[7] + a2*b[11] + a3;
    }
}

// Kernel 1: rel transforms (B=4, J=24, 3x4) -> ws. Slot 0 = cano, 1..4 = batches.
__global__ void tf_kernel(const float* __restrict__ poses,
                          const float* __restrict__ cano_pose,
                          const float* __restrict__ rest_joints,
                          float* __restrict__ rel_out) {
    __shared__ float M[5][J][12];
    __shared__ float relj[J][3];
    __shared__ float cinv[J][12];
    const int t = threadIdx.x;

    if (t < J) {
        int p = PARENTS[t];
        for (int k = 0; k < 3; ++k) {
            float v = rest_joints[t*3+k];
            if (p >= 0) v -= rest_joints[p*3+k];
            relj[t][k] = v;
        }
    }
    __syncthreads();

    for (int task = t; task < 5*J; task += blockDim.x) {
        int s = task / J, j = task % J;
        const float* rv = (s == 0) ? (cano_pose + j*3) : (poses + ((s-1)*J + j)*3);
        float rx = rv[0], ry = rv[1], rz = rv[2];
        float ang = sqrtf(rx*rx + ry*ry + rz*rz) + 1e-8f;
        float ax = rx/ang, ay = ry/ang, az = rz/ang;
        float s_ = sinf(ang), c_ = cosf(ang), ic = 1.0f - c_;
        float* m = M[s][j];
        m[0]  = 1.0f - ic*(ay*ay + az*az);
        m[1]  = -s_*az + ic*ax*ay;
        m[2]  =  s_*ay + ic*ax*az;
        m[3]  = relj[j][0];
        m[4]  =  s_*az + ic*ax*ay;
        m[5]  = 1.0f - ic*(ax*ax + az*az);
        m[6]  = -s_*ax + ic*ay*az;
        m[7]  = relj[j][1];
        m[8]  = -s_*ay + ic*ax*az;
        m[9]  =  s_*ax + ic*ay*az;
        m[10] = 1.0f - ic*(ax*ax + ay*ay);
        m[11] = relj[j][2];
    }
    __syncthreads();

    if (t < 5) {
        for (int i = 1; i < J; ++i) {
            int p = PARENTS[i];
            float r[12];
            compose34(M[t][p], M[t][i], r);
            for (int k = 0; k < 12; ++k) M[t][i][k] = r[k];
        }
    }
    __syncthreads();

    for (int task = t; task < 5*J; task += blockDim.x) {
        int s = task / J, j = task % J;
        float* m = M[s][j];
        float rjx = rest_joints[j*3], rjy = rest_joints[j*3+1], rjz = rest_joints[j*3+2];
        m[3]  -= m[0]*rjx + m[1]*rjy + m[2]*rjz;
        m[7]  -= m[4]*rjx + m[5]*rjy + m[6]*rjz;
        m[11] -= m[8]*rjx + m[9]*rjy + m[10]*rjz;
    }
    __syncthreads();

    if (t < J) {
        const float* m = M[0][t];
        float* ci = cinv[t];
        ci[0] = m[0]; ci[1] = m[4]; ci[2]  = m[8];
        ci[4] = m[1]; ci[5] = m[5]; ci[6]  = m[9];
        ci[8] = m[2]; ci[9] = m[6]; ci[10] = m[10];
        ci[3]  = -(ci[0]*m[3] + ci[1]*m[7] + ci[2]*m[11]);
        ci[7]  = -(ci[4]*m[3] + ci[5]*m[7] + ci[6]*m[11]);
        ci[11] = -(ci[8]*m[3] + ci[9]*m[7] + ci[10]*m[11]);
    }
    __syncthreads();

    for (int task = t; task < 4*J; task += blockDim.x) {
        int b = task / J, j = task % J;
        float r[12];
        compose34(M[b+1][j], cinv[j], r);
        for (int k = 0; k < 12; ++k) rel_out[(b*J + j)*12 + k] = r[k];
    }
}

// Kernel 2: LDS-tiled transpose [J][D][H][W] f32 -> [D][H][W][CPAD] fp16.
// Each block owns TILE voxels. Write phase: per channel-pair, 256 lanes load
// 1KB CONTIGUOUS from ONE plane (copy-like; only one plane in flight per
// instruction), pack fp16 pair, deposit to LDS [v][32ch] with an 8B-block XOR
// swizzle (b8 ^= v&7; lanes span consecutive v -> ~8-way worst). Read phase:
// pure contiguous 1KB/instr global stores of the tile. Both global streams
// are now long contiguous bursts (the pattern that hits ~6-7 TB/s).
__global__ __launch_bounds__(256) void transpose_kernel(
    const float* __restrict__ g, unsigned short* __restrict__ tg) {
    __shared__ unsigned short lds[TILE * CPAD];   // 32 KB
    const int t = threadIdx.x;
    const size_t tile0 = (size_t)blockIdx.x * TILE;

    // ---- write phase: channel pairs -> LDS (swizzled) ----
    #pragma unroll
    for (int r = 0; r < TILE/256; ++r) {
        const int v = t + r*256;
        const float* src = g + tile0 + v;
        #pragma unroll
        for (int p = 0; p < 12; ++p) {
            float a = __builtin_nontemporal_load(src + (size_t)(2*p)   * DHW);
            float b = __builtin_nontemporal_load(src + (size_t)(2*p+1) * DHW);
            unsigned int pk = (unsigned int)f2h(a) | ((unsigned int)f2h(b) << 16);
            int b8 = (p >> 1) ^ (v & 7);           // swizzled 8B-block
            *(unsigned int*)((char*)lds + v*64 + b8*8 + (p & 1)*4) = pk;
        }
    }
    __syncthreads();

    // ---- read phase: contiguous 16B chunks out ----
    const int nchunk = TILE * 4;   // 16B chunks in tile
    #pragma unroll
    for (int i0 = 0; i0 < nchunk; i0 += 256) {
        int i = i0 + t;
        int v = i >> 2, q = i & 3;
        u16x8 o;
        if (q == 3) {
            #pragma unroll
            for (int k = 0; k < 8; ++k) o[k] = 0;
        } else {
            int s = v & 7;
            unsigned long long lo = *(const unsigned long long*)
                ((const char*)lds + v*64 + ((2*q)     ^ s)*8);
            unsigned long long hi = *(const unsigned long long*)
                ((const char*)lds + v*64 + ((2*q + 1) ^ s)*8);
            union { unsigned long long q2[2]; u16x8 vv; } u;
            u.q2[0] = lo; u.q2[1] = hi;
            o = u.vv;
        }
        *(u16x8*)(tg + tile0*CPAD + (size_t)i*8) = o;
    }
}

// f32 original-layout trilinear sample (hand grids, rare)
__device__ inline void sample_grid_f32(const float* __restrict__ g,
                                       float cx, float cy, float cz, float* w) {
    const float S = (float)RES;
    float fx = ((cx + 1.0f) * S - 1.0f) * 0.5f;
    float fy = ((cy + 1.0f) * S - 1.0f) * 0.5f;
    float fz = ((cz + 1.0f) * S - 1.0f) * 0.5f;
    fx = fminf(fmaxf(fx, 0.0f), S - 1.0f);
    fy = fminf(fmaxf(fy, 0.0f), S - 1.0f);
    fz = fminf(fmaxf(fz, 0.0f), S - 1.0f);
    float x0f = floorf(fx), y0f = floorf(fy), z0f = floorf(fz);
    float tx = fx - x0f, ty = fy - y0f, tz = fz - z0f;
    int x0 = (int)x0f, y0 = (int)y0f, z0 = (int)z0f;
    int x1 = x0 < RES-1 ? x0+1 : RES-1;
    int y1 = y0 < RES-1 ? y0+1 : RES-1;
    int z1 = z0 < RES-1 ? z0+1 : RES-1;
    int b00 = (z0*RES + y0)*RES;
    int b01 = (z0*RES + y1)*RES;
    int b10 = (z1*RES + y0)*RES;
    int b11 = (z1*RES + y1)*RES;
    float wx0 = 1.0f - tx, wx1 = tx;
    float wy0 = 1.0f - ty, wy1 = ty;
    float wz0 = 1.0f - tz, wz1 = tz;
    float w000 = wz0*wy0*wx0, w001 = wz0*wy0*wx1;
    float w010 = wz0*wy1*wx0, w011 = wz0*wy1*wx1;
    float w100 = wz1*wy0*wx0, w101 = wz1*wy0*wx1;
    float w110 = wz1*wy1*wx0, w111 = wz1*wy1*wx1;
    #pragma unroll
    for (int c = 0; c < J; ++c) {
        const float* gc = g + (size_t)c * DHW;
        w[c] = gc[b00+x0]*w000 + gc[b00+x1]*w001
             + gc[b01+x0]*w010 + gc[b01+x1]*w011
             + gc[b10+x0]*w100 + gc[b10+x1]*w101
             + gc[b11+x0]*w110 + gc[b11+x1]*w111;
    }
}

// Kernel 3: gather from channel-innermost fp16 grid + blend + transform
__global__ __launch_bounds__(256) void skin_kernel(
    const float* __restrict__ verts,
    const unsigned short* __restrict__ tg,   // [DHW][CPAD] fp16
    const float* __restrict__ lgrid,
    const float* __restrict__ rgrid,
    const float* __restrict__ rel,
    const float* __restrict__ bbox_extend, const float* __restrict__ bbox_center,
    const float* __restrict__ lhand_extend, const float* __restrict__ lhand_center,
    const float* __restrict__ rhand_extend, const float* __restrict__ rhand_center,
    float* __restrict__ out, int N, int total) {
    __shared__ float srel[J*12];
    int gid = blockIdx.x * blockDim.x + threadIdx.x;
    int b = gid / N;   // uniform within a block (N % 256 == 0)

    for (int i = threadIdx.x; i < J*12; i += blockDim.x)
        srel[i] = rel[b*J*12 + i];
    __syncthreads();

    if (gid >= total) return;

    float vx = verts[(size_t)gid*3 + 0];
    float vy = verts[(size_t)gid*3 + 1];
    float vz = verts[(size_t)gid*3 + 2];

    float be = bbox_extend[0];
    float px = (vx - bbox_center[0]) / be * 2.0f;
    float py = (vy - bbox_center[1]) / be * 2.0f;
    float pz = (vz - bbox_center[2]) / be * 2.0f;

    const float S = (float)RES;
    float fx = ((px + 1.0f) * S - 1.0f) * 0.5f;
    float fy = ((py + 1.0f) * S - 1.0f) * 0.5f;
    float fz = ((pz + 1.0f) * S - 1.0f) * 0.5f;
    fx = fminf(fmaxf(fx, 0.0f), S - 1.0f);
    fy = fminf(fmaxf(fy, 0.0f), S - 1.0f);
    fz = fminf(fmaxf(fz, 0.0f), S - 1.0f);
    float x0f = floorf(fx), y0f = floorf(fy), z0f = floorf(fz);
    float tx = fx - x0f, ty = fy - y0f, tz = fz - z0f;
    int x0 = (int)x0f, y0 = (int)y0f, z0 = (int)z0f;
    int x1 = x0 < RES-1 ? x0+1 : RES-1;
    int y1 = y0 < RES-1 ? y0+1 : RES-1;
    int z1 = z0 < RES-1 ? z0+1 : RES-1;

    float w[J];
    #pragma unroll
    for (int c = 0; c < J; ++c) w[c] = 0.0f;

    #pragma unroll
    for (int dz = 0; dz < 2; ++dz) {
        int zz = dz ? z1 : z0;
        float wz = dz ? tz : 1.0f - tz;
        #pragma unroll
        for (int dy = 0; dy < 2; ++dy) {
            int yy = dy ? y1 : y0;
            float wzy = wz * (dy ? ty : 1.0f - ty);
            #pragma unroll
            for (int dx = 0; dx < 2; ++dx) {
                int xx = dx ? x1 : x0;
                float wc = wzy * (dx ? tx : 1.0f - tx);
                const unsigned short* vp = tg + ((size_t)((zz*RES + yy)*RES + xx) * CPAD);
                u16x8 a0 = *(const u16x8*)(vp);
                u16x8 a1 = *(const u16x8*)(vp + 8);
                u16x8 a2 = *(const u16x8*)(vp + 16);
                #pragma unroll
                for (int k = 0; k < 8; ++k) {
                    w[k +  0] += wc * h2f(a0[k]);
                    w[k +  8] += wc * h2f(a1[k]);
                    w[k + 16] += wc * h2f(a2[k]);
                }
            }
        }
    }

    // hand overrides (rare: ~0.6% of points each)
    float le = lhand_extend[0];
    float plx = px*le + lhand_center[0];
    float ply = py*le + lhand_center[1];
    float plz = pz*le + lhand_center[2];
    if (plx >= -1.0f && plx <= 1.0f && ply >= -1.0f && ply <= 1.0f &&
        plz >= -1.0f && plz <= 1.0f) {
        sample_grid_f32(lgrid, plx, ply, plz, w);
    }
    float re = rhand_extend[0];
    float prx = px*re + rhand_center[0];
    float pry = py*re + rhand_center[1];
    float prz = pz*re + rhand_center[2];
    if (prx >= -1.0f && prx <= 1.0f && pry >= -1.0f && pry <= 1.0f &&
        prz >= -1.0f && prz <= 1.0f) {
        sample_grid_f32(rgrid, prx, pry, prz, w);
    }

    // blend: M = sum_j w[j] * rel[b][j]
    float m[12];
    #pragma unroll
    for (int k = 0; k < 12; ++k) m[k] = 0.0f;
    #pragma unroll
    for (int j = 0; j < J; ++j) {
        float wj = w[j];
        const float* rj = &srel[j*12];
        #pragma unroll
        for (int k = 0; k < 12; ++k) m[k] += wj * rj[k];
    }

    float ox = m[0]*vx + m[1]*vy + m[2]*vz  + m[3];
    float oy = m[4]*vx + m[5]*vy + m[6]*vz  + m[7];
    float oz = m[8]*vx + m[9]*vy + m[10]*vz + m[11];

    out[(size_t)gid*3 + 0] = ox;
    out[(size_t)gid*3 + 1] = oy;
    out[(size_t)gid*3 + 2] = oz;
}

// Fallback (original f32-layout path) if workspace is too small
__global__ __launch_bounds__(256) void skin_kernel_f32(
    const float* __restrict__ verts,
    const float* __restrict__ wgrid,
    const float* __restrict__ lgrid,
    const float* __restrict__ rgrid,
    const float* __restrict__ rel,
    const float* __restrict__ bbox_extend, const float* __restrict__ bbox_center,
    const float* __restrict__ lhand_extend, const float* __restrict__ lhand_center,
    const float* __restrict__ rhand_extend, const float* __restrict__ rhand_center,
    float* __restrict__ out, int N, int total) {
    __shared__ float srel[J*12];
    int gid = blockIdx.x * blockDim.x + threadIdx.x;
    int b = gid / N;
    for (int i = threadIdx.x; i < J*12; i += blockDim.x)
        srel[i] = rel[b*J*12 + i];
    __syncthreads();
    if (gid >= total) return;
    float vx = verts[(size_t)gid*3 + 0];
    float vy = verts[(size_t)gid*3 + 1];
    float vz = verts[(size_t)gid*3 + 2];
    float be = bbox_extend[0];
    float px = (vx - bbox_center[0]) / be * 2.0f;
    float py = (vy - bbox_center[1]) / be * 2.0f;
    float pz = (vz - bbox_center[2]) / be * 2.0f;
    float w[J];
    sample_grid_f32(wgrid, px, py, pz, w);
    float le = lhand_extend[0];
    float plx = px*le + lhand_center[0];
    float ply = py*le + lhand_center[1];
    float plz = pz*le + lhand_center[2];
    if (plx >= -1.0f && plx <= 1.0f && ply >= -1.0f && ply <= 1.0f &&
        plz >= -1.0f && plz <= 1.0f) sample_grid_f32(lgrid, plx, ply, plz, w);
    float re = rhand_extend[0];
    float prx = px*re + rhand_center[0];
    float pry = py*re + rhand_center[1];
    float prz = pz*re + rhand_center[2];
    if (prx >= -1.0f && prx <= 1.0f && pry >= -1.0f && pry <= 1.0f &&
        prz >= -1.0f && prz <= 1.0f) sample_grid_f32(rgrid, prx, pry, prz, w);
    float m[12];
    #pragma unroll
    for (int k = 0; k < 12; ++k) m[k] = 0.0f;
    #pragma unroll
    for (int j = 0; j < J; ++j) {
        float wj = w[j];
        const float* rj = &srel[j*12];
        #pragma unroll
        for (int k = 0; k < 12; ++k) m[k] += wj * rj[k];
    }
    out[(size_t)gid*3 + 0] = m[0]*vx + m[1]*vy + m[2]*vz  + m[3];
    out[(size_t)gid*3 + 1] = m[4]*vx + m[5]*vy + m[6]*vz  + m[7];
    out[(size_t)gid*3 + 2] = m[8]*vx + m[9]*vy + m[10]*vz + m[11];
}

extern "C" void kernel_launch(void* const* d_in, const int* in_sizes, int n_in,
                              void* d_out, int out_size, void* d_ws, size_t ws_size,
                              hipStream_t stream) {
    const float* verts       = (const float*)d_in[0];
    const float* poses       = (const float*)d_in[1];
    const float* cano_pose   = (const float*)d_in[2];
    const float* rest_joints = (const float*)d_in[3];
    const float* wgrid       = (const float*)d_in[4];
    const float* lgrid       = (const float*)d_in[5];
    const float* rgrid       = (const float*)d_in[6];
    const float* bbox_extend = (const float*)d_in[7];
    const float* bbox_center = (const float*)d_in[8];
    const float* lhand_extend= (const float*)d_in[9];
    const float* lhand_center= (const float*)d_in[10];
    const float* rhand_extend= (const float*)d_in[11];
    const float* rhand_center= (const float*)d_in[12];

    float* out = (float*)d_out;
    float* rel = (float*)d_ws;                         // 4608 B
    unsigned short* tg = (unsigned short*)((char*)d_ws + 8192); // [DHW][CPAD] fp16

    const int B = 4;
    const int total = in_sizes[0] / 3;
    const int N = total / B;
    const size_t need = 8192 + (size_t)DHW * CPAD * 2;

    tf_kernel<<<1, 128, 0, stream>>>(poses, cano_pose, rest_joints, rel);

    const int block = 256;
    if (ws_size >= need) {
        transpose_kernel<<<DHW / TILE, block, 0, stream>>>(wgrid, tg);
        skin_kernel<<<(total + block - 1) / block, block, 0, stream>>>(
            verts, tg, lgrid, rgrid, rel,
            bbox_extend, bbox_center, lhand_extend, lhand_center,
            rhand_extend, rhand_center, out, N, total);
    } else {
        skin_kernel_f32<<<(total + block - 1) / block, block, 0, stream>>>(
            verts, wgrid, lgrid, rgrid, rel,
            bbox_extend, bbox_center, lhand_extend, lhand_center,
            rhand_extend, rhand_center, out, N, total);
    }
}